// Round 24
// baseline (104.683 us; speedup 1.0000x reference)
//
#include <hip/hip_runtime.h>
#include <hip/hip_bf16.h>
#include <math.h>

namespace {

constexpr int D  = 128;
constexpr int TN = 64;
constexpr int NB = 8;     // batches per fused block

typedef _Float16 h2 __attribute__((ext_vector_type(2)));

__device__ __forceinline__ unsigned pack_h2(float a, float b) {
    h2 v; v.x = (_Float16)a; v.y = (_Float16)b;
    return __builtin_bit_cast(unsigned, v);
}
__device__ __forceinline__ float2 unp_h2(unsigned u) {
    h2 v = __builtin_bit_cast(h2, u);
    return make_float2((float)v.x, (float)v.y);
}
__device__ __forceinline__ h2 bch2(unsigned u) { return __builtin_bit_cast(h2, u); }
__device__ __forceinline__ unsigned bcu(h2 v) { return __builtin_bit_cast(unsigned, v); }
__device__ __forceinline__ float fdot2f(unsigned a, unsigned b, float c) {
#if __has_builtin(__builtin_amdgcn_fdot2)
    return __builtin_amdgcn_fdot2(__builtin_bit_cast(h2, a),
                                  __builtin_bit_cast(h2, b), c, false);
#else
    const float2 fa = unp_h2(a), fb = unp_h2(b);
    return fmaf(fa.x, fb.x, fmaf(fa.y, fb.y, c));
#endif
}

// d_ws layout (both k-paired f16):
//   N2 [64][1024]  uint (pairs over k of N[128][1024])   256 KB
//   M2 [512][128]  uint (pairs over k of M[1024][128])   256 KB

// ---------------- K0: precompute N2 and M2 (k-paired f16, r20-proven) ----------------
__global__ __launch_bounds__(256)
void k0_nm(const float* __restrict__ WQ, const float* __restrict__ WK,
           const float* __restrict__ WV, const float* __restrict__ WO,
           unsigned* __restrict__ N2, unsigned* __restrict__ M2)
{
    const int t = blockIdx.x * 256 + threadIdx.x;   // 0..65535
    {   // N2[kk][col]: pair of N[2kk][col], N[2kk+1][col]
        const int kk = t >> 10, col = t & 1023;
        const int h = col >> 7, d = col & 127;
        const float* wq0 = WQ + (size_t)(2 * kk) * D + h * 16;
        const float* wq1 = wq0 + D;
        const float* wk  = WK + (size_t)d * D + h * 16;
        float a0 = 0.f, a1 = 0.f;
        #pragma unroll
        for (int j = 0; j < 16; ++j) {
            a0 = fmaf(wq0[j], wk[j], a0);
            a1 = fmaf(wq1[j], wk[j], a1);
        }
        N2[t] = pack_h2(0.25f * a0, 0.25f * a1);
    }
    {   // M2[kk][e]: pair of M[2kk][e], M[2kk+1][e];  k = h*128+d
        const int kk = t >> 7, e = t & 127;
        const int k0 = 2 * kk;
        const int h = k0 >> 7, d = k0 & 127;
        const float* wv0 = WV + (size_t)d * D + h * 16;
        const float* wv1 = wv0 + D;
        const float* wo  = WO + (size_t)(h * 16) * D + e;
        float b0 = 0.f, b1 = 0.f;
        #pragma unroll
        for (int j = 0; j < 16; ++j) {
            const float w_ = wo[(size_t)j * D];
            b0 = fmaf(wv0[j], w_, b0);
            b1 = fmaf(wv1[j], w_, b1);
        }
        M2[t] = pack_h2(b0, b1);
    }
}

// ---------------- fused: qk=c@N2 -> 8x attention (2-barrier) -> out=s@M2 ----------------
// Each wave head-self-contained: P never crosses waves (wave-internal lgkm fence only).
// Barriers/batch: 4 -> 2. LDS ~36.5 KB -> 4 blocks/CU.
__global__ __launch_bounds__(256, 2)
void k_fused(const float* __restrict__ center, const float* __restrict__ neighbors,
             const unsigned* __restrict__ N2, const unsigned* __restrict__ M2,
             float* __restrict__ out)
{
    __shared__ __align__(16) float nb_lds[TN * D / 2];  // 16 KB f16 tokens; uint2 slot (t<<5)|(fc^(t&7))
    __shared__ __align__(16) float qs8f[NB * 512];      // 16 KB f16: qk (rotated) -> s (k-paired linear)
    __shared__ __align__(16) unsigned c2u[NB * 64];     // 2 KB f16 k-paired center rows
    __shared__ __align__(16) unsigned Pu[8 * 64];       // 2 KB: P[head][token] as dup f16 pairs {p,p}

    const int tid = threadIdx.x;           // 0..255
    const int w   = tid >> 6;              // wave 0..3 (attention: owns heads 2w,2w+1)
    const int l   = tid & 63;
    const size_t rb = (size_t)blockIdx.x * NB;

    uint2* nbu  = (uint2*)nb_lds;
    uint2* qs8u = (uint2*)qs8f;

    // ---- stage c2 (k-paired f16) ----
    {
        const int r = tid >> 5, f = tid & 31;
        const float4 g = ((const float4*)(center + (rb + r) * (size_t)D))[f];
        c2u[r * 64 + 2 * f]     = pack_h2(g.x, g.y);
        c2u[r * 64 + 2 * f + 1] = pack_h2(g.z, g.w);
    }
    __syncthreads();                       // c2 visible

    // ================= k1-part: qk8 = c @ N (fdot2, kk-paired, r23-proven) =================
    {
        const uint4* N2u4 = (const uint4*)N2;   // row kk = 256 uint4
        float4 acc[NB];
        #pragma unroll
        for (int r = 0; r < NB; ++r) acc[r] = make_float4(0.f, 0.f, 0.f, 0.f);

        #pragma unroll 2
        for (int kk2 = 0; kk2 < 32; ++kk2) {
            const int kk = 2 * kk2;
            const uint4 ua = N2u4[(size_t)kk * 256 + tid];
            const uint4 ub = N2u4[(size_t)(kk + 1) * 256 + tid];
            #pragma unroll
            for (int r = 0; r < NB; ++r) {
                const uint2 cp = *reinterpret_cast<const uint2*>(&c2u[r * 64 + kk]);
                acc[r].x = fdot2f(cp.x, ua.x, acc[r].x);
                acc[r].y = fdot2f(cp.x, ua.y, acc[r].y);
                acc[r].z = fdot2f(cp.x, ua.z, acc[r].z);
                acc[r].w = fdot2f(cp.x, ua.w, acc[r].w);
                acc[r].x = fdot2f(cp.y, ub.x, acc[r].x);
                acc[r].y = fdot2f(cp.y, ub.y, acc[r].y);
                acc[r].z = fdot2f(cp.y, ub.z, acc[r].z);
                acc[r].w = fdot2f(cp.y, ub.w, acc[r].w);
            }
        }
        const int fc = tid & 31;
        const int qslot = (tid & ~31) | (((fc & 7) << 2) | (fc >> 3));  // rotated qk layout
        #pragma unroll
        for (int r = 0; r < NB; ++r)
            qs8u[r * 256 + qslot] =
                make_uint2(pack_h2(acc[r].x, acc[r].y), pack_h2(acc[r].z, acc[r].w));
    }

    // ---- NOW load batch-0 nb into staging regs (not live across the GEMM above) ----
    float4 st[8];
    {
        const float4* g0 = (const float4*)(neighbors + rb * TN * D);
        #pragma unroll
        for (int i = 0; i < 8; ++i) st[i] = g0[i * 256 + tid];
    }
    __syncthreads();                       // qk visible

    // ================= per-batch attention loop (2 barriers/batch) =================
    #pragma unroll 1
    for (int bb = 0; bb < NB; ++bb) {
        // ---- commit staged nb registers -> f16 swizzled LDS ----
        #pragma unroll
        for (int i = 0; i < 8; ++i) {
            const int fi = i * 256 + tid;
            const int t  = fi >> 5;
            const int fc = fi & 31;
            nbu[(t << 5) | (fc ^ (t & 7))] =
                make_uint2(pack_h2(st[i].x, st[i].y), pack_h2(st[i].z, st[i].w));
        }
        __syncthreads();                   // bar 1: nb staged

        // ---- issue next batch's nb loads; they fly during phases A/D ----
        if (bb + 1 < NB) {
            const float4* gn = (const float4*)(neighbors + (rb + bb + 1) * TN * D);
            #pragma unroll
            for (int i = 0; i < 8; ++i) st[i] = gn[i * 256 + tid];
        }

        const uint2*    nb2 = (const uint2*)nb_lds;
        const uint2*    qku = qs8u + bb * 256;
        const unsigned* cb2 = c2u + bb * 64;

        // ---- phase A: wave w scores all 64 tokens for heads 2w,2w+1; wave-local softmax ----
        const int tg = l & 15;
        const int q  = l >> 4;
        const int h0 = 2 * w;

        unsigned cr[16];
        {
            const uint4* cb4 = (const uint4*)(cb2 + q * 16);
            *reinterpret_cast<uint4*>(&cr[0])  = cb4[0];
            *reinterpret_cast<uint4*>(&cr[4])  = cb4[1];
            *reinterpret_cast<uint4*>(&cr[8])  = cb4[2];
            *reinterpret_cast<uint4*>(&cr[12]) = cb4[3];
        }

        float sc0[4] = {0.f, 0.f, 0.f, 0.f};
        float sc1[4] = {0.f, 0.f, 0.f, 0.f};
        float s0a = 0.f, s0b = 0.f;
        #pragma unroll
        for (int jj = 0; jj < 8; ++jj) {
            const int rfc = (jj << 2) | q;     // rotated slot of fc=(q<<3)|jj
            const int fc  = (q << 3) | jj;
            const uint2 kv0p = qku[h0 * 32 + rfc];
            const uint2 kv1p = qku[(h0 + 1) * 32 + rfc];
            const unsigned cpa = cr[2 * jj], cpb = cr[2 * jj + 1];
            s0a = fdot2f(cpa, kv0p.x, fdot2f(cpb, kv0p.y, s0a));
            s0b = fdot2f(cpa, kv1p.x, fdot2f(cpb, kv1p.y, s0b));
            #pragma unroll
            for (int k = 0; k < 4; ++k) {
                const int t = tg + (k << 4);
                const uint2 u = nb2[(t << 5) | (fc ^ (t & 7))];
                sc0[k] = fdot2f(u.x, kv0p.x, fdot2f(u.y, kv0p.y, sc0[k]));
                sc1[k] = fdot2f(u.x, kv1p.x, fdot2f(u.y, kv1p.y, sc1[k]));
            }
        }
        #pragma unroll
        for (int k = 0; k < 4; ++k) {
            sc0[k] += __shfl_xor(sc0[k], 16);  sc0[k] += __shfl_xor(sc0[k], 32);
            sc1[k] += __shfl_xor(sc1[k], 16);  sc1[k] += __shfl_xor(sc1[k], 32);
        }
        s0a += __shfl_xor(s0a, 16);  s0a += __shfl_xor(s0a, 32);
        s0b += __shfl_xor(s0b, 16);  s0b += __shfl_xor(s0b, 32);

        float m0 = fmaxf(fmaxf(sc0[0], sc0[1]), fmaxf(sc0[2], sc0[3]));
        float m1 = fmaxf(fmaxf(sc1[0], sc1[1]), fmaxf(sc1[2], sc1[3]));
        #pragma unroll
        for (int off = 8; off >= 1; off >>= 1) {
            m0 = fmaxf(m0, __shfl_xor(m0, off));
            m1 = fmaxf(m1, __shfl_xor(m1, off));
        }
        m0 = fmaxf(m0, s0a);
        m1 = fmaxf(m1, s0b);
        float e0v[4], e1v[4];
        float sum0 = 0.f, sum1 = 0.f;
        #pragma unroll
        for (int k = 0; k < 4; ++k) {
            e0v[k] = __expf(sc0[k] - m0);  sum0 += e0v[k];
            e1v[k] = __expf(sc1[k] - m1);  sum1 += e1v[k];
        }
        #pragma unroll
        for (int off = 8; off >= 1; off >>= 1) {
            sum0 += __shfl_xor(sum0, off);
            sum1 += __shfl_xor(sum1, off);
        }
        const float ec0 = __expf(s0a - m0);
        const float ec1 = __expf(s0b - m1);
        const float inv0 = 1.0f / (sum0 + ec0);
        const float inv1 = 1.0f / (sum1 + ec1);
        const float pctr0 = ec0 * inv0;    // uniform across wave; stays in registers
        const float pctr1 = ec1 * inv1;
        if (q == 0) {                      // publish P per-head-contiguous: Pu[h][t]
            #pragma unroll
            for (int k = 0; k < 4; ++k) {
                const int t = tg + (k << 4);
                const float p0 = e0v[k] * inv0;
                const float p1 = e1v[k] * inv1;
                Pu[h0 * 64 + t]       = pack_h2(p0, p0);
                Pu[(h0 + 1) * 64 + t] = pack_h2(p1, p1);
            }
        }
        // wave-internal visibility: LDS ops are in-order per wave; drain then read
        asm volatile("s_waitcnt lgkmcnt(0)" ::: "memory");

        // ---- phase D': lane (hh, fc2) sums s[2w+hh][fc2*4..+3] over ALL 64 tokens ----
        {
            const int hh  = l >> 5;
            const int fc2 = l & 31;
            const unsigned* Ph = Pu + (h0 + hh) * 64;
            h2 a01 = {0, 0}, a23 = {0, 0};
            #pragma unroll
            for (int tt = 0; tt < 64; tt += 4) {
                const uint4 pq = *reinterpret_cast<const uint4*>(&Ph[tt]);
                {
                    const int t = tt;
                    const uint2 u = nb2[(t << 5) | (fc2 ^ (t & 7))];
                    const h2 p = bch2(pq.x);
                    a01 += p * bch2(u.x);  a23 += p * bch2(u.y);
                }
                {
                    const int t = tt + 1;
                    const uint2 u = nb2[(t << 5) | (fc2 ^ (t & 7))];
                    const h2 p = bch2(pq.y);
                    a01 += p * bch2(u.x);  a23 += p * bch2(u.y);
                }
                {
                    const int t = tt + 2;
                    const uint2 u = nb2[(t << 5) | (fc2 ^ (t & 7))];
                    const h2 p = bch2(pq.z);
                    a01 += p * bch2(u.x);  a23 += p * bch2(u.y);
                }
                {
                    const int t = tt + 3;
                    const uint2 u = nb2[(t << 5) | (fc2 ^ (t & 7))];
                    const h2 p = bch2(pq.w);
                    a01 += p * bch2(u.x);  a23 += p * bch2(u.y);
                }
            }
            // center seed from in-register pctr (uniform)
            const float pcv = hh ? pctr1 : pctr0;
            h2 pch; pch.x = (_Float16)pcv; pch.y = (_Float16)pcv;
            const uint2 cc = *reinterpret_cast<const uint2*>(&cb2[2 * fc2]);
            a01 += pch * bch2(cc.x);
            a23 += pch * bch2(cc.y);
            // write s (f16 k-paired, linear): slot (h)*32 + fc2
            qs8u[bb * 256 + (h0 + hh) * 32 + fc2] = make_uint2(bcu(a01), bcu(a23));
        }
        __syncthreads();                   // bar 2: nb consumed; s visible for k3
    }

    // ================= k3-part: out = s @ M (fdot2, kk-paired, r23-proven) =================
    {
        const int cg = tid & 31;
        const int kg = tid >> 5;
        const int c4i = cg << 2;
        const int kb2 = kg << 6;           // kk base (64 pairs per k-split group)

        float4 acc[NB];
        #pragma unroll
        for (int r = 0; r < NB; ++r) acc[r] = make_float4(0.f, 0.f, 0.f, 0.f);

        const uint4* M2u4 = (const uint4*)M2;           // row kk = 32 uint4
        const unsigned* sp2 = (const unsigned*)qs8f;    // s pairs: [r*512 + kk]

        #pragma unroll 2
        for (int k4 = 0; k4 < 32; ++k4) {
            const int kk = kb2 + 2 * k4;
            const uint4 ua = M2u4[(size_t)kk * 32 + cg];
            const uint4 ub = M2u4[(size_t)(kk + 1) * 32 + cg];
            #pragma unroll
            for (int r = 0; r < NB; ++r) {
                const uint2 sv = *reinterpret_cast<const uint2*>(&sp2[r * 512 + kk]);
                acc[r].x = fdot2f(sv.x, ua.x, acc[r].x);
                acc[r].y = fdot2f(sv.x, ua.y, acc[r].y);
                acc[r].z = fdot2f(sv.x, ua.z, acc[r].z);
                acc[r].w = fdot2f(sv.x, ua.w, acc[r].w);
                acc[r].x = fdot2f(sv.y, ub.x, acc[r].x);
                acc[r].y = fdot2f(sv.y, ub.y, acc[r].y);
                acc[r].z = fdot2f(sv.y, ub.z, acc[r].z);
                acc[r].w = fdot2f(sv.y, ub.w, acc[r].w);
            }
        }
        __syncthreads();                   // all s reads done; nb+qs8 regions free
        // partials: 32 KB split across nb_lds (kg 0-3) and qs8f (kg 4-7)
        float* baseW = (kg < 4) ? nb_lds : qs8f;
        const int kgm = kg & 3;
        #pragma unroll
        for (int r = 0; r < NB; ++r)
            *reinterpret_cast<float4*>(&baseW[(kgm * 8 + r) * 128 + c4i]) = acc[r];
        __syncthreads();

        {
            const int r = tid >> 5;
            float4 sum = make_float4(0.f, 0.f, 0.f, 0.f);
            #pragma unroll
            for (int g = 0; g < 8; ++g) {
                const float* bg = (g < 4) ? nb_lds : qs8f;
                const float4 p = *reinterpret_cast<const float4*>(
                    &bg[((g & 3) * 8 + r) * 128 + c4i]);
                sum.x += p.x; sum.y += p.y; sum.z += p.z; sum.w += p.w;
            }
            *reinterpret_cast<float4*>(out + (rb + r) * D + c4i) = sum;
        }
    }
}

} // namespace

extern "C" void kernel_launch(void* const* d_in, const int* in_sizes, int n_in,
                              void* d_out, int out_size, void* d_ws, size_t ws_size,
                              hipStream_t stream) {
    const float* center    = (const float*)d_in[0];
    const float* neighbors = (const float*)d_in[1];
    const float* WQ        = (const float*)d_in[2];
    const float* WK        = (const float*)d_in[3];
    const float* WV        = (const float*)d_in[4];
    const float* WO        = (const float*)d_in[5];
    float* outp            = (float*)d_out;

    const int B = in_sizes[0] / D;   // 8192

    unsigned* N2 = (unsigned*)d_ws;          // 64*1024 uint (256 KB)
    unsigned* M2 = N2 + 64 * 1024;           // 512*128 uint (256 KB)

    hipLaunchKernelGGL(k0_nm,   dim3(256),    dim3(256), 0, stream, WQ, WK, WV, WO, N2, M2);
    hipLaunchKernelGGL(k_fused, dim3(B / NB), dim3(256), 0, stream, center, neighbors, N2, M2, outp);
}

// Round 25
// 101.577 us; speedup vs baseline: 1.0306x; 1.0306x over previous
//
#include <hip/hip_runtime.h>
#include <hip/hip_bf16.h>
#include <math.h>

namespace {

constexpr int D  = 128;
constexpr int TN = 64;
constexpr int NB = 8;     // batches per fused block

typedef _Float16 h2 __attribute__((ext_vector_type(2)));

__device__ __forceinline__ unsigned pack_h2(float a, float b) {
    h2 v; v.x = (_Float16)a; v.y = (_Float16)b;
    return __builtin_bit_cast(unsigned, v);
}
__device__ __forceinline__ float2 unp_h2(unsigned u) {
    h2 v = __builtin_bit_cast(h2, u);
    return make_float2((float)v.x, (float)v.y);
}
__device__ __forceinline__ h2 bch2(unsigned u) { return __builtin_bit_cast(h2, u); }
__device__ __forceinline__ float fdot2f(unsigned a, unsigned b, float c) {
#if __has_builtin(__builtin_amdgcn_fdot2)
    return __builtin_amdgcn_fdot2(__builtin_bit_cast(h2, a),
                                  __builtin_bit_cast(h2, b), c, false);
#else
    const float2 fa = unp_h2(a), fb = unp_h2(b);
    return fmaf(fa.x, fb.x, fmaf(fa.y, fb.y, c));
#endif
}

// d_ws layout (both k-paired f16):
//   N2 [64][1024]  uint (pairs over k of N[128][1024])   256 KB
//   M2 [512][128]  uint (pairs over k of M[1024][128])   256 KB

// ---------------- K0: precompute N2 and M2 (k-paired f16, r20-proven) ----------------
__global__ __launch_bounds__(256)
void k0_nm(const float* __restrict__ WQ, const float* __restrict__ WK,
           const float* __restrict__ WV, const float* __restrict__ WO,
           unsigned* __restrict__ N2, unsigned* __restrict__ M2)
{
    const int t = blockIdx.x * 256 + threadIdx.x;   // 0..65535
    {   // N2[kk][col]: pair of N[2kk][col], N[2kk+1][col]
        const int kk = t >> 10, col = t & 1023;
        const int h = col >> 7, d = col & 127;
        const float* wq0 = WQ + (size_t)(2 * kk) * D + h * 16;
        const float* wq1 = wq0 + D;
        const float* wk  = WK + (size_t)d * D + h * 16;
        float a0 = 0.f, a1 = 0.f;
        #pragma unroll
        for (int j = 0; j < 16; ++j) {
            a0 = fmaf(wq0[j], wk[j], a0);
            a1 = fmaf(wq1[j], wk[j], a1);
        }
        N2[t] = pack_h2(0.25f * a0, 0.25f * a1);
    }
    {   // M2[kk][e]: pair of M[2kk][e], M[2kk+1][e];  k = h*128+d
        const int kk = t >> 7, e = t & 127;
        const int k0 = 2 * kk;
        const int h = k0 >> 7, d = k0 & 127;
        const float* wv0 = WV + (size_t)d * D + h * 16;
        const float* wv1 = wv0 + D;
        const float* wo  = WO + (size_t)(h * 16) * D + e;
        float b0 = 0.f, b1 = 0.f;
        #pragma unroll
        for (int j = 0; j < 16; ++j) {
            const float w_ = wo[(size_t)j * D];
            b0 = fmaf(wv0[j], w_, b0);
            b1 = fmaf(wv1[j], w_, b1);
        }
        M2[t] = pack_h2(b0, b1);
    }
}

// ---------------- fused: qk=c@N2 -> 8x attention -> out=s@M2 (r22 + DS diet) -------------
// LDS ~37.9 KB -> 4 blocks/CU.
__global__ __launch_bounds__(256, 2)
void k_fused(const float* __restrict__ center, const float* __restrict__ neighbors,
             const unsigned* __restrict__ N2, const unsigned* __restrict__ M2,
             float* __restrict__ out)
{
    __shared__ __align__(16) float nb_lds[TN * D / 2];  // 16 KB f16 tokens; uint2 slot (t<<5)|(fc^(t&7))
    __shared__ __align__(16) float qs8f[NB * 512];      // 16 KB f16: qk (rotated) -> s (k-paired linear)
    __shared__ __align__(16) unsigned c2u[NB * 64];     // 2 KB f16 k-paired center rows
    __shared__ __align__(16) unsigned Pu[TN * 12];      // 3 KB: P as duplicated f16 pairs {p,p}
    __shared__ float red_pc[8];

    const int tid = threadIdx.x;           // 0..255
    const int w   = tid >> 6;              // wave 0..3 (attention: owns heads 2w,2w+1)
    const int l   = tid & 63;
    const size_t rb = (size_t)blockIdx.x * NB;

    uint2* nbu  = (uint2*)nb_lds;
    uint2* qs8u = (uint2*)qs8f;

    // ---- stage c2 (k-paired f16) ----
    {
        const int r = tid >> 5, f = tid & 31;
        const float4 g = ((const float4*)(center + (rb + r) * (size_t)D))[f];
        c2u[r * 64 + 2 * f]     = pack_h2(g.x, g.y);
        c2u[r * 64 + 2 * f + 1] = pack_h2(g.z, g.w);
    }
    __syncthreads();                       // c2 visible

    // ================= k1-part: qk8 = c @ N (fdot2, kk-paired c reads) =================
    {
        const uint4* N2u4 = (const uint4*)N2;   // row kk = 256 uint4
        float4 acc[NB];
        #pragma unroll
        for (int r = 0; r < NB; ++r) acc[r] = make_float4(0.f, 0.f, 0.f, 0.f);

        #pragma unroll 2
        for (int kk2 = 0; kk2 < 32; ++kk2) {
            const int kk = 2 * kk2;
            const uint4 ua = N2u4[(size_t)kk * 256 + tid];        // 4 cols' k-pair (kk)
            const uint4 ub = N2u4[(size_t)(kk + 1) * 256 + tid];  // (kk+1)
            #pragma unroll
            for (int r = 0; r < NB; ++r) {
                const uint2 cp = *reinterpret_cast<const uint2*>(&c2u[r * 64 + kk]);
                acc[r].x = fdot2f(cp.x, ua.x, acc[r].x);
                acc[r].y = fdot2f(cp.x, ua.y, acc[r].y);
                acc[r].z = fdot2f(cp.x, ua.z, acc[r].z);
                acc[r].w = fdot2f(cp.x, ua.w, acc[r].w);
                acc[r].x = fdot2f(cp.y, ub.x, acc[r].x);
                acc[r].y = fdot2f(cp.y, ub.y, acc[r].y);
                acc[r].z = fdot2f(cp.y, ub.z, acc[r].z);
                acc[r].w = fdot2f(cp.y, ub.w, acc[r].w);
            }
        }
        const int fc = tid & 31;
        const int qslot = (tid & ~31) | (((fc & 7) << 2) | (fc >> 3));  // rotated qk layout
        #pragma unroll
        for (int r = 0; r < NB; ++r)
            qs8u[r * 256 + qslot] =
                make_uint2(pack_h2(acc[r].x, acc[r].y), pack_h2(acc[r].z, acc[r].w));
    }

    // ---- NOW load batch-0 nb into staging regs (not live across the GEMM above) ----
    float4 st[8];
    {
        const float4* g0 = (const float4*)(neighbors + rb * TN * D);
        #pragma unroll
        for (int i = 0; i < 8; ++i) st[i] = g0[i * 256 + tid];
    }
    __syncthreads();                       // qk visible

    // ================= per-batch attention loop =================
    #pragma unroll 1
    for (int bb = 0; bb < NB; ++bb) {
        // ---- commit staged nb registers -> f16 swizzled LDS ----
        #pragma unroll
        for (int i = 0; i < 8; ++i) {
            const int fi = i * 256 + tid;
            const int t  = fi >> 5;
            const int fc = fi & 31;
            nbu[(t << 5) | (fc ^ (t & 7))] =
                make_uint2(pack_h2(st[i].x, st[i].y), pack_h2(st[i].z, st[i].w));
        }
        __syncthreads();                   // nb staged

        // ---- issue next batch's nb loads; they fly during phases A-E ----
        if (bb + 1 < NB) {
            const float4* gn = (const float4*)(neighbors + (rb + bb + 1) * TN * D);
            #pragma unroll
            for (int i = 0; i < 8; ++i) st[i] = gn[i * 256 + tid];
        }

        const uint2*    nb2 = (const uint2*)nb_lds;
        const uint2*    qku = qs8u + bb * 256;
        const unsigned* cb2 = c2u + bb * 64;

        // ---- phase A: wave w scores all 64 tokens for heads 2w,2w+1; wave-local softmax ----
        const int tg = l & 15;
        const int q  = l >> 4;
        const int h0 = 2 * w;

        // hoist this lane's c-octave (16 uints) into regs: 4 uint4 LDS reads (was 16 scalar)
        unsigned cr[16];
        {
            const uint4* cb4 = (const uint4*)(cb2 + q * 16);
            *reinterpret_cast<uint4*>(&cr[0])  = cb4[0];
            *reinterpret_cast<uint4*>(&cr[4])  = cb4[1];
            *reinterpret_cast<uint4*>(&cr[8])  = cb4[2];
            *reinterpret_cast<uint4*>(&cr[12]) = cb4[3];
        }

        float sc0[4] = {0.f, 0.f, 0.f, 0.f};
        float sc1[4] = {0.f, 0.f, 0.f, 0.f};
        float s0a = 0.f, s0b = 0.f;
        #pragma unroll
        for (int jj = 0; jj < 8; ++jj) {
            const int rfc = (jj << 2) | q;     // rotated slot of fc=(q<<3)|jj
            const int fc  = (q << 3) | jj;
            const uint2 kv0p = qku[h0 * 32 + rfc];
            const uint2 kv1p = qku[(h0 + 1) * 32 + rfc];
            const unsigned cpa = cr[2 * jj], cpb = cr[2 * jj + 1];   // static idx (unrolled)
            s0a = fdot2f(cpa, kv0p.x, fdot2f(cpb, kv0p.y, s0a));
            s0b = fdot2f(cpa, kv1p.x, fdot2f(cpb, kv1p.y, s0b));
            #pragma unroll
            for (int k = 0; k < 4; ++k) {
                const int t = tg + (k << 4);
                const uint2 u = nb2[(t << 5) | (fc ^ (t & 7))];
                sc0[k] = fdot2f(u.x, kv0p.x, fdot2f(u.y, kv0p.y, sc0[k]));
                sc1[k] = fdot2f(u.x, kv1p.x, fdot2f(u.y, kv1p.y, sc1[k]));
            }
        }
        #pragma unroll
        for (int k = 0; k < 4; ++k) {
            sc0[k] += __shfl_xor(sc0[k], 16);  sc0[k] += __shfl_xor(sc0[k], 32);
            sc1[k] += __shfl_xor(sc1[k], 16);  sc1[k] += __shfl_xor(sc1[k], 32);
        }
        s0a += __shfl_xor(s0a, 16);  s0a += __shfl_xor(s0a, 32);
        s0b += __shfl_xor(s0b, 16);  s0b += __shfl_xor(s0b, 32);

        float m0 = fmaxf(fmaxf(sc0[0], sc0[1]), fmaxf(sc0[2], sc0[3]));
        float m1 = fmaxf(fmaxf(sc1[0], sc1[1]), fmaxf(sc1[2], sc1[3]));
        #pragma unroll
        for (int off = 8; off >= 1; off >>= 1) {
            m0 = fmaxf(m0, __shfl_xor(m0, off));
            m1 = fmaxf(m1, __shfl_xor(m1, off));
        }
        m0 = fmaxf(m0, s0a);
        m1 = fmaxf(m1, s0b);
        float e0v[4], e1v[4];
        float sum0 = 0.f, sum1 = 0.f;
        #pragma unroll
        for (int k = 0; k < 4; ++k) {
            e0v[k] = __expf(sc0[k] - m0);  sum0 += e0v[k];
            e1v[k] = __expf(sc1[k] - m1);  sum1 += e1v[k];
        }
        #pragma unroll
        for (int off = 8; off >= 1; off >>= 1) {
            sum0 += __shfl_xor(sum0, off);
            sum1 += __shfl_xor(sum1, off);
        }
        const float ec0 = __expf(s0a - m0);
        const float ec1 = __expf(s0b - m1);
        const float inv0 = 1.0f / (sum0 + ec0);
        const float inv1 = 1.0f / (sum1 + ec1);
        if (q == 0) {
            #pragma unroll
            for (int k = 0; k < 4; ++k) {
                const int t = tg + (k << 4);
                const float p0 = e0v[k] * inv0;
                const float p1 = e1v[k] * inv1;
                *reinterpret_cast<uint2*>(&Pu[t * 12 + h0]) =
                    make_uint2(pack_h2(p0, p0), pack_h2(p1, p1));
            }
            if (tg == 0) {
                red_pc[h0]     = ec0 * inv0;
                red_pc[h0 + 1] = ec1 * inv1;
            }
        }
        __syncthreads();   // bar: P complete

        // ---- phase D (pk_fma, r22-proven): wave w sums its 16 tokens ----
        const int hl  = l >> 5;
        const int fc2 = l & 31;
        h2 pk00 = {0, 0}, pk01 = {0, 0};
        h2 pk10 = {0, 0}, pk11 = {0, 0};
        h2 pk20 = {0, 0}, pk21 = {0, 0};
        h2 pk30 = {0, 0}, pk31 = {0, 0};
        #pragma unroll
        for (int tt = 0; tt < 16; ++tt) {
            const int t = w * 16 + tt;
            const uint2 u = nb2[(t << 5) | (fc2 ^ (t & 7))];
            const h2 u0 = bch2(u.x), u1 = bch2(u.y);
            const uint4 pp = *reinterpret_cast<const uint4*>(&Pu[t * 12 + hl * 4]);
            const h2 p0 = bch2(pp.x), p1 = bch2(pp.y), p2 = bch2(pp.z), p3 = bch2(pp.w);
            pk00 += p0 * u0;  pk01 += p0 * u1;
            pk10 += p1 * u0;  pk11 += p1 * u1;
            pk20 += p2 * u0;  pk21 += p2 * u1;
            pk30 += p3 * u0;  pk31 += p3 * u1;
        }
        {
            float4 pf;
            pf = make_float4((float)pk00.x, (float)pk00.y, (float)pk01.x, (float)pk01.y);
            ((float4*)nb_lds)[w * 256 + (hl * 4 + 0) * 32 + fc2] = pf;
            pf = make_float4((float)pk10.x, (float)pk10.y, (float)pk11.x, (float)pk11.y);
            ((float4*)nb_lds)[w * 256 + (hl * 4 + 1) * 32 + fc2] = pf;
            pf = make_float4((float)pk20.x, (float)pk20.y, (float)pk21.x, (float)pk21.y);
            ((float4*)nb_lds)[w * 256 + (hl * 4 + 2) * 32 + fc2] = pf;
            pf = make_float4((float)pk30.x, (float)pk30.y, (float)pk31.x, (float)pk31.y);
            ((float4*)nb_lds)[w * 256 + (hl * 4 + 3) * 32 + fc2] = pf;
        }
        __syncthreads();   // bar: partials ready

        // ---- phase E: combine partials + center seed; write s (f16 k-paired, linear) ----
        {
            const int hE = tid >> 5;
            const int fE = tid & 31;
            float4 sum = make_float4(0.f, 0.f, 0.f, 0.f);
            #pragma unroll
            for (int ww = 0; ww < 4; ++ww) {
                const float4 p = ((const float4*)nb_lds)[ww * 256 + hE * 32 + fE];
                sum.x += p.x; sum.y += p.y; sum.z += p.z; sum.w += p.w;
            }
            const float pc = red_pc[hE];
            const float2 ca = unp_h2(cb2[2 * fE]), cb = unp_h2(cb2[2 * fE + 1]);
            sum.x = fmaf(pc, ca.x, sum.x);
            sum.y = fmaf(pc, ca.y, sum.y);
            sum.z = fmaf(pc, cb.x, sum.z);
            sum.w = fmaf(pc, cb.y, sum.w);
            qs8u[bb * 256 + tid] =
                make_uint2(pack_h2(sum.x, sum.y), pack_h2(sum.z, sum.w));
        }
        __syncthreads();   // bar: partials consumed; next commit may overwrite nb
    }

    // ================= k3-part: out = s @ M (fdot2, kk-paired s reads) =================
    {
        const int cg = tid & 31;
        const int kg = tid >> 5;
        const int c4i = cg << 2;
        const int kb2 = kg << 6;           // kk base (64 pairs per k-split group)

        float4 acc[NB];
        #pragma unroll
        for (int r = 0; r < NB; ++r) acc[r] = make_float4(0.f, 0.f, 0.f, 0.f);

        const uint4* M2u4 = (const uint4*)M2;           // row kk = 32 uint4
        const unsigned* sp2 = (const unsigned*)qs8f;    // s pairs: [r*512 + kk]

        #pragma unroll 2
        for (int k4 = 0; k4 < 32; ++k4) {
            const int kk = kb2 + 2 * k4;
            const uint4 ua = M2u4[(size_t)kk * 32 + cg];
            const uint4 ub = M2u4[(size_t)(kk + 1) * 32 + cg];
            #pragma unroll
            for (int r = 0; r < NB; ++r) {
                const uint2 sv = *reinterpret_cast<const uint2*>(&sp2[r * 512 + kk]);
                acc[r].x = fdot2f(sv.x, ua.x, acc[r].x);
                acc[r].y = fdot2f(sv.x, ua.y, acc[r].y);
                acc[r].z = fdot2f(sv.x, ua.z, acc[r].z);
                acc[r].w = fdot2f(sv.x, ua.w, acc[r].w);
                acc[r].x = fdot2f(sv.y, ub.x, acc[r].x);
                acc[r].y = fdot2f(sv.y, ub.y, acc[r].y);
                acc[r].z = fdot2f(sv.y, ub.z, acc[r].z);
                acc[r].w = fdot2f(sv.y, ub.w, acc[r].w);
            }
        }
        __syncthreads();                   // all s reads done; nb+qs8 regions free
        // partials: 32 KB split across nb_lds (kg 0-3) and qs8f (kg 4-7)
        float* baseW = (kg < 4) ? nb_lds : qs8f;
        const int kgm = kg & 3;
        #pragma unroll
        for (int r = 0; r < NB; ++r)
            *reinterpret_cast<float4*>(&baseW[(kgm * 8 + r) * 128 + c4i]) = acc[r];
        __syncthreads();

        {
            const int r = tid >> 5;
            float4 sum = make_float4(0.f, 0.f, 0.f, 0.f);
            #pragma unroll
            for (int g = 0; g < 8; ++g) {
                const float* bg = (g < 4) ? nb_lds : qs8f;
                const float4 p = *reinterpret_cast<const float4*>(
                    &bg[((g & 3) * 8 + r) * 128 + c4i]);
                sum.x += p.x; sum.y += p.y; sum.z += p.z; sum.w += p.w;
            }
            *reinterpret_cast<float4*>(out + (rb + r) * D + c4i) = sum;
        }
    }
}

} // namespace

extern "C" void kernel_launch(void* const* d_in, const int* in_sizes, int n_in,
                              void* d_out, int out_size, void* d_ws, size_t ws_size,
                              hipStream_t stream) {
    const float* center    = (const float*)d_in[0];
    const float* neighbors = (const float*)d_in[1];
    const float* WQ        = (const float*)d_in[2];
    const float* WK        = (const float*)d_in[3];
    const float* WV        = (const float*)d_in[4];
    const float* WO        = (const float*)d_in[5];
    float* outp            = (float*)d_out;

    const int B = in_sizes[0] / D;   // 8192

    unsigned* N2 = (unsigned*)d_ws;          // 64*1024 uint (256 KB)
    unsigned* M2 = N2 + 64 * 1024;           // 512*128 uint (256 KB)

    hipLaunchKernelGGL(k0_nm,   dim3(256),    dim3(256), 0, stream, WQ, WK, WV, WO, N2, M2);
    hipLaunchKernelGGL(k_fused, dim3(B / NB), dim3(256), 0, stream, center, neighbors, N2, M2, outp);
}